// Round 20
// baseline (232.748 us; speedup 1.0000x reference)
//
#include <hip/hip_runtime.h>
#include <math.h>

#define N_NODES 10000
#define B_SZ 2
#define T_STEPS 8
#define M_COLS 16
#define BN 20000
#define NM 160000

typedef __attribute__((ext_vector_type(8))) short short8;
typedef __attribute__((ext_vector_type(4))) float f32x4;

__device__ __forceinline__ float b2f(unsigned short u) {
  union { unsigned int i; float f; } x; x.i = ((unsigned int)u) << 16; return x.f;
}
__device__ __forceinline__ unsigned short f2b(float f) {
  unsigned int x = __float_as_uint(f);
  return (unsigned short)((x + 0x7fffu + ((x >> 16) & 1u)) >> 16);
}
__device__ __forceinline__ float sigm(float x) {
  return 1.f / (1.f + __expf(-x));
}
__device__ __forceinline__ float tanhfast(float x) {
  float xm = fmaxf(x, -15.f);
  float e = __expf(-2.f * xm);
  return (1.f - e) / (1.f + e);
}

// ---------------- CSR build ----------------
__global__ __launch_bounds__(256) void k_count_prep(const int* __restrict__ dst, int* __restrict__ cnt, int E,
                                                    int eb,
                                                    const float* __restrict__ Wih, const float* __restrict__ W2,
                                                    const float* __restrict__ Whh,
                                                    unsigned short* __restrict__ Wbih,
                                                    unsigned short* __restrict__ W2t,
                                                    unsigned short* __restrict__ Whi,
                                                    unsigned short* __restrict__ Wlo) {
  if ((int)blockIdx.x < eb) {
    int e = blockIdx.x*256 + threadIdx.x;
    if (e < E) atomicAdd(&cnt[dst[e]], 1);
  } else {
    int i = (blockIdx.x - eb)*256 + threadIdx.x;
    if (i >= 12288) return;
    Wbih[i] = f2b(Wih[i]);
    int p = i >> 12, rem = i & 4095, c = rem >> 6, k = rem & 63;
    W2t[i] = f2b(W2[p*4096 + k*64 + c]);
    float v = Whh[i];
    unsigned short h = f2b(v);
    Whi[i] = h;
    Wlo[i] = f2b(v - b2f(h));
  }
}

__global__ __launch_bounds__(256) void k_scan(const int* __restrict__ cntin, int* __restrict__ rowp,
                                              int* __restrict__ cntz, int n) {
  const int K = 40;
  int t = threadIdx.x;
  int beg = t*K;
  int end = beg + K < n ? beg + K : n;
  int s = 0;
  for (int i = beg; i < end; ++i) s += cntin[i];
  int lane = t & 63, w = t >> 6;
  int v = s;
#pragma unroll
  for (int off = 1; off < 64; off <<= 1) {
    int u = __shfl_up(v, off, 64);
    if (lane >= off) v += u;
  }
  __shared__ int wsum[4];
  if (lane == 63) wsum[w] = v;
  __syncthreads();
  int woff = 0;
  for (int i = 0; i < w; ++i) woff += wsum[i];
  int run = woff + v - s;
  for (int i = beg; i < end; ++i) {
    rowp[i] = run;
    run += cntin[i];
    cntz[i] = 0;
  }
  if (t == 255) rowp[n] = run;
}

__global__ __launch_bounds__(256) void k_fill(const int* __restrict__ src, const int* __restrict__ dst,
                                              const float* __restrict__ val, const int* __restrict__ rowp,
                                              int* __restrict__ cur, int* __restrict__ csrs,
                                              float* __restrict__ csrv, int E) {
  int e = blockIdx.x*256 + threadIdx.x;
  if (e >= E) return;
  int d = dst[e];
  int p = atomicAdd(&cur[d], 1);
  int slot = rowp[d] + p;
  csrs[slot] = src[e];
  csrv[slot] = val[e];
}

// ---------------- layer 1 (fused), 4-deep unrolled gathers ----------------
__global__ __launch_bounds__(256) void k_spmmA(const float* __restrict__ x, float* __restrict__ Z1,
                                               const int* __restrict__ rowp, const int* __restrict__ csrs,
                                               const float* __restrict__ csrv) {
  int i = blockIdx.x*256 + threadIdx.x;
  int n = i >> 4, m = i & 15;
  int b = m >> 3, t = m & 7;
  int s = rowp[n], e = rowp[n+1];
  const float* xb = x + b*(N_NODES*T_STEPS) + t;
  float a0 = 0.f, a1 = 0.f, a2 = 0.f, a3 = 0.f;
  int k = s;
  for (; k + 3 < e; k += 4) {
    int s0 = csrs[k], s1 = csrs[k+1], s2 = csrs[k+2], s3 = csrs[k+3];
    float v0 = csrv[k], v1 = csrv[k+1], v2 = csrv[k+2], v3 = csrv[k+3];
    float x0 = xb[s0*T_STEPS], x1 = xb[s1*T_STEPS], x2 = xb[s2*T_STEPS], x3 = xb[s3*T_STEPS];
    a0 = fmaf(v0, x0, a0);
    a1 = fmaf(v1, x1, a1);
    a2 = fmaf(v2, x2, a2);
    a3 = fmaf(v3, x3, a3);
  }
  for (; k < e; ++k) a0 = fmaf(csrv[k], xb[csrs[k]*T_STEPS], a0);
  Z1[i] = (a0 + a1) + (a2 + a3);
}

__global__ __launch_bounds__(256) void k_spmmB_l1(const float* __restrict__ x, const float* __restrict__ Z1,
                                                  const int* __restrict__ rowp, const int* __restrict__ csrs,
                                                  const float* __restrict__ csrv,
                                                  const float* __restrict__ W1, const float* __restrict__ b1,
                                                  unsigned short* __restrict__ H1b) {
  int i = blockIdx.x*256 + threadIdx.x;
  int n = i >> 4, m = i & 15;
  int b = m >> 3, t = m & 7;
  int s = rowp[n], e = rowp[n+1];
  float a0 = 0.f, a1 = 0.f, a2 = 0.f, a3 = 0.f;
  int k = s;
  for (; k + 3 < e; k += 4) {
    int s0 = csrs[k], s1 = csrs[k+1], s2 = csrs[k+2], s3 = csrs[k+3];
    float v0 = csrv[k], v1 = csrv[k+1], v2 = csrv[k+2], v3 = csrv[k+3];
    float g0 = Z1[s0*16 + m], g1 = Z1[s1*16 + m], g2 = Z1[s2*16 + m], g3 = Z1[s3*16 + m];
    a0 = fmaf(v0, g0, a0);
    a1 = fmaf(v1, g1, a1);
    a2 = fmaf(v2, g2, a2);
    a3 = fmaf(v3, g3, a3);
  }
  for (; k < e; ++k) a0 = fmaf(csrv[k], Z1[csrs[k]*16 + m], a0);
  float z2 = (a0 + a1) + (a2 + a3);
  float z0 = x[b*(N_NODES*T_STEPS) + n*T_STEPS + t];
  float z1 = Z1[i];
  unsigned short* dst = H1b + (size_t)i*64;
  union { uint4 v; unsigned short s[8]; } o;
#pragma unroll
  for (int g = 0; g < 8; ++g) {
#pragma unroll
    for (int j = 0; j < 8; ++j) {
      int c = g*8 + j;
      float v = fmaf(z0, W1[c], fmaf(z1, W1[64+c], fmaf(z2, W1[128+c], b1[c])));
      o.s[j] = f2b(v > 0.f ? v : 0.f);
    }
    ((uint4*)dst)[g] = o.v;
  }
}

// ---------------- layer 2 pass 1: chunked spmm, 8-deep unrolled gather ----------------
__global__ __launch_bounds__(256) void k_spmmC(const unsigned short* __restrict__ Zin,
                                               unsigned short* __restrict__ Zout,
                                               const int* __restrict__ rowp, const int* __restrict__ csrs,
                                               const float* __restrict__ csrv) {
  int c = blockIdx.x & 7;
  int grp = blockIdx.x >> 3;
  int n = grp*16 + (threadIdx.x >> 4);
  int l = threadIdx.x & 15;
  int off = c*128 + l*8;
  int s = rowp[n], e = rowp[n+1];
  float acc[8] = {0,0,0,0,0,0,0,0};
  int k = s;
  for (; k + 7 < e; k += 8) {
    int si[8]; float vi[8];
#pragma unroll
    for (int u = 0; u < 8; ++u) { si[u] = csrs[k+u]; vi[u] = csrv[k+u]; }
    union { uint4 u; unsigned short s[8]; } z[8];
#pragma unroll
    for (int u = 0; u < 8; ++u) z[u].u = *(const uint4*)(Zin + (size_t)si[u]*1024 + off);
#pragma unroll
    for (int u = 0; u < 8; ++u)
#pragma unroll
      for (int j = 0; j < 8; ++j) acc[j] = fmaf(vi[u], b2f(z[u].s[j]), acc[j]);
  }
  for (; k < e; ++k) {
    int s0 = csrs[k];
    float v0 = csrv[k];
    union { uint4 u; unsigned short s[8]; } z0;
    z0.u = *(const uint4*)(Zin + (size_t)s0*1024 + off);
#pragma unroll
    for (int j = 0; j < 8; ++j) acc[j] = fmaf(v0, b2f(z0.s[j]), acc[j]);
  }
  union { uint4 u; unsigned short s[8]; } o;
#pragma unroll
  for (int j = 0; j < 8; ++j) o.s[j] = f2b(acc[j]);
  *(uint4*)(Zout + (size_t)n*1024 + off) = o.u;
}

// ---------------- layer 2 pass 2 FUSED with dense epilogue (8-deep phase 1) ----------------
__global__ __launch_bounds__(256) void k_spmmC2_l2m(const unsigned short* __restrict__ H1b,
                                                    const unsigned short* __restrict__ ZB1,
                                                    const int* __restrict__ rowp, const int* __restrict__ csrs,
                                                    const float* __restrict__ csrv,
                                                    const unsigned short* __restrict__ Wt,
                                                    const float* __restrict__ b2,
                                                    unsigned short* __restrict__ OUT2b) {
  __shared__ unsigned short Z2L[16][144];
  int c = blockIdx.x & 7;
  int grp = blockIdx.x >> 3;
  int tid = threadIdx.x;
  {
    int ni = tid >> 4, l = tid & 15;
    int n = grp*16 + ni;
    int off = c*128 + l*8;
    int s = rowp[n], e = rowp[n+1];
    float acc[8] = {0,0,0,0,0,0,0,0};
    int k = s;
    for (; k + 7 < e; k += 8) {
      int si[8]; float vi[8];
#pragma unroll
      for (int u = 0; u < 8; ++u) { si[u] = csrs[k+u]; vi[u] = csrv[k+u]; }
      union { uint4 u; unsigned short s[8]; } z[8];
#pragma unroll
      for (int u = 0; u < 8; ++u) z[u].u = *(const uint4*)(ZB1 + (size_t)si[u]*1024 + off);
#pragma unroll
      for (int u = 0; u < 8; ++u)
#pragma unroll
        for (int j = 0; j < 8; ++j) acc[j] = fmaf(vi[u], b2f(z[u].s[j]), acc[j]);
    }
    for (; k < e; ++k) {
      int s0 = csrs[k];
      float v0 = csrv[k];
      union { uint4 u; unsigned short s[8]; } z0;
      z0.u = *(const uint4*)(ZB1 + (size_t)s0*1024 + off);
#pragma unroll
      for (int j = 0; j < 8; ++j) acc[j] = fmaf(v0, b2f(z0.s[j]), acc[j]);
    }
    union { uint4 v; unsigned short s[8]; } o;
#pragma unroll
    for (int j = 0; j < 8; ++j) o.s[j] = f2b(acc[j]);
    *(uint4*)&Z2L[ni][(l >> 3)*72 + (l & 7)*8] = o.v;
  }
  __syncthreads();
  int w = tid >> 6, lane = tid & 63;
  int lr = lane & 15, h4 = lane >> 4;
  int q = w & 1, ch = w >> 1;
  int m = 2*c + q;
  short8 aH[2], aZ1[2], aZ2[2];
#pragma unroll
  for (int kc = 0; kc < 2; ++kc) {
    size_t nm = ((size_t)(grp*16 + lr)*16 + m);
    aH[kc]  = *(const short8*)((const short*)H1b + nm*64 + kc*32 + h4*8);
    aZ1[kc] = *(const short8*)((const short*)ZB1 + nm*64 + kc*32 + h4*8);
    aZ2[kc] = *(const short8*)&Z2L[lr][q*72 + kc*32 + h4*8];
  }
  const short* Bp = (const short*)Wt;
  f32x4 accb[2];
#pragma unroll
  for (int ct2 = 0; ct2 < 2; ++ct2) {
    int col = (ch*2 + ct2)*16 + lr;
    f32x4 cc = {0.f, 0.f, 0.f, 0.f};
#pragma unroll
    for (int kc = 0; kc < 2; ++kc) {
      short8 b0 = *(const short8*)(Bp + col*64 + kc*32 + h4*8);
      short8 b1 = *(const short8*)(Bp + 4096 + col*64 + kc*32 + h4*8);
      short8 b2f_ = *(const short8*)(Bp + 8192 + col*64 + kc*32 + h4*8);
      cc = __builtin_amdgcn_mfma_f32_16x16x32_bf16(aH[kc],  b0,   cc, 0, 0, 0);
      cc = __builtin_amdgcn_mfma_f32_16x16x32_bf16(aZ1[kc], b1,   cc, 0, 0, 0);
      cc = __builtin_amdgcn_mfma_f32_16x16x32_bf16(aZ2[kc], b2f_, cc, 0, 0, 0);
    }
    accb[ct2] = cc;
  }
  int t = m & 7, bi = m >> 3;
#pragma unroll
  for (int ct2 = 0; ct2 < 2; ++ct2) {
    int col = (ch*2 + ct2)*16 + lr;
    float bb = b2[col];
#pragma unroll
    for (int r = 0; r < 4; ++r) {
      int n2 = grp*16 + h4*4 + r;
      float v = accb[ct2][r] + bb;
      OUT2b[((size_t)((t*2 + bi)*N_NODES + n2))*64 + col] = f2b(v > 0.f ? v : 0.f);
    }
  }
}

// ---------------- fused GRU (FROZEN: r14/r16 exact) ----------------
__global__ __launch_bounds__(256, 2) void k_gru(const unsigned short* __restrict__ OUT2b,
                                                const unsigned short* __restrict__ Whhi,
                                                const unsigned short* __restrict__ Whlo,
                                                const unsigned short* __restrict__ Wihb,
                                                const float* __restrict__ bih,
                                                const float* __restrict__ bhh,
                                                const float* __restrict__ Whead,
                                                const float* __restrict__ bhead,
                                                float* __restrict__ y) {
  extern __shared__ char smem[];
  uint4* WF = (uint4*)smem;
  float* HSb = (float*)(smem + 49152);
  int tid = threadIdx.x;
  for (int idx = tid; idx < 48*64; idx += 256) {
    int f = idx >> 6, ln = idx & 63;
    int lrr = ln & 15, h4r = ln >> 4;
    int g = (f < 24) ? f : f - 24;
    int ct = g >> 1, kc = g & 1;
    const unsigned short* src = (f < 24) ? Whhi : Whlo;
    WF[idx] = *(const uint4*)(src + (ct*16 + lrr)*64 + kc*32 + h4r*8);
  }
  int w = tid >> 6, lane = tid & 63;
  int lr = lane & 15, h4 = lane >> 4;
  float* hs = HSb + w*(16*68);
  for (int i = lane; i < 16*68; i += 64) hs[i] = 0.f;
  __syncthreads();
  int Wv = blockIdx.x*4 + w;
  if (Wv >= 1250) return;
  int base = Wv*16;
  int row0 = base + lr;
  int b0 = row0 >= N_NODES ? 1 : 0;
  int n0 = row0 - b0*N_NODES;

  float cR[4], cZ[4], bNi[4], bNh[4];
#pragma unroll
  for (int cr = 0; cr < 4; ++cr) {
    int col = cr*16 + lr;
    cR[cr]  = bih[col] + bhh[col];
    cZ[cr]  = bih[64+col] + bhh[64+col];
    bNi[cr] = bih[128+col];
    bNh[cr] = bhh[128+col];
  }
  float hreg[4][4];
#pragma unroll
  for (int cr = 0; cr < 4; ++cr)
#pragma unroll
    for (int j = 0; j < 4; ++j) hreg[cr][j] = 0.f;
  const short* O = (const short*)OUT2b;
  const short* Wx = (const short*)Wihb;

#pragma unroll 1
  for (int t = 0; t < 8; ++t) {
    short8 ax[2];
    size_t ab0 = ((size_t)((t*2 + b0)*N_NODES + n0))*64;
    ax[0] = *(const short8*)(O + ab0 + h4*8);
    ax[1] = *(const short8*)(O + ab0 + 32 + h4*8);
    short8 ahi[2], alo[2];
#pragma unroll
    for (int kc = 0; kc < 2; ++kc) {
      const float* hp = hs + lr*68 + kc*32 + h4*8;
      float4 v0 = *(const float4*)hp;
      float4 v1 = *(const float4*)(hp + 4);
      float hv[8];
      hv[0]=v0.x; hv[1]=v0.y; hv[2]=v0.z; hv[3]=v0.w;
      hv[4]=v1.x; hv[5]=v1.y; hv[6]=v1.z; hv[7]=v1.w;
      union { short8 v; unsigned short s[8]; } uh, ul;
#pragma unroll
      for (int j = 0; j < 8; ++j) {
        unsigned short hb = (unsigned short)(__float_as_uint(hv[j]) >> 16);
        uh.s[j] = hb;
        ul.s[j] = f2b(hv[j] - b2f(hb));
      }
      ahi[kc] = uh.v; alo[kc] = ul.v;
    }
    f32x4 aR[4], aZ[4], aNx[4], aNh[4];
#pragma unroll
    for (int cr = 0; cr < 4; ++cr) {
      f32x4 zz = {0.f,0.f,0.f,0.f};
      aR[cr] = zz; aZ[cr] = zz; aNx[cr] = zz; aNh[cr] = zz;
    }
#pragma unroll
    for (int g = 0; g < 6; ++g) {
      short8 fh[4], fl[4], fx[4];
#pragma unroll
      for (int p = 0; p < 4; ++p) {
        int pair = g*4 + p;
        fh[p] = *(const short8*)&WF[pair*64 + lane];
        fl[p] = *(const short8*)&WF[(24 + pair)*64 + lane];
        fx[p] = *(const short8*)(Wx + ((pair >> 1)*16 + lr)*64 + (pair & 1)*32 + h4*8);
      }
      __builtin_amdgcn_sched_barrier(0);
#pragma unroll
      for (int p = 0; p < 4; ++p) {
        int pair = g*4 + p;
        int ct = pair >> 1, kc = pair & 1;
        if (ct < 4) {
          aR[ct] = __builtin_amdgcn_mfma_f32_16x16x32_bf16(ax[kc],  fx[p], aR[ct], 0, 0, 0);
          aR[ct] = __builtin_amdgcn_mfma_f32_16x16x32_bf16(ahi[kc], fh[p], aR[ct], 0, 0, 0);
          aR[ct] = __builtin_amdgcn_mfma_f32_16x16x32_bf16(ahi[kc], fl[p], aR[ct], 0, 0, 0);
          aR[ct] = __builtin_amdgcn_mfma_f32_16x16x32_bf16(alo[kc], fh[p], aR[ct], 0, 0, 0);
        } else if (ct < 8) {
          int cc = ct - 4;
          aZ[cc] = __builtin_amdgcn_mfma_f32_16x16x32_bf16(ax[kc],  fx[p], aZ[cc], 0, 0, 0);
          aZ[cc] = __builtin_amdgcn_mfma_f32_16x16x32_bf16(ahi[kc], fh[p], aZ[cc], 0, 0, 0);
          aZ[cc] = __builtin_amdgcn_mfma_f32_16x16x32_bf16(ahi[kc], fl[p], aZ[cc], 0, 0, 0);
          aZ[cc] = __builtin_amdgcn_mfma_f32_16x16x32_bf16(alo[kc], fh[p], aZ[cc], 0, 0, 0);
        } else {
          int cc = ct - 8;
          aNx[cc] = __builtin_amdgcn_mfma_f32_16x16x32_bf16(ax[kc],  fx[p], aNx[cc], 0, 0, 0);
          aNh[cc] = __builtin_amdgcn_mfma_f32_16x16x32_bf16(ahi[kc], fh[p], aNh[cc], 0, 0, 0);
          aNh[cc] = __builtin_amdgcn_mfma_f32_16x16x32_bf16(ahi[kc], fl[p], aNh[cc], 0, 0, 0);
          aNh[cc] = __builtin_amdgcn_mfma_f32_16x16x32_bf16(alo[kc], fh[p], aNh[cc], 0, 0, 0);
        }
      }
    }
#pragma unroll
    for (int cr = 0; cr < 4; ++cr)
#pragma unroll
      for (int j = 0; j < 4; ++j) {
        float r = sigm(aR[cr][j] + cR[cr]);
        float z = sigm(aZ[cr][j] + cZ[cr]);
        float nn = tanhfast(aNx[cr][j] + bNi[cr] + r*(aNh[cr][j] + bNh[cr]));
        float hv = (1.f - z)*nn + z*hreg[cr][j];
        hreg[cr][j] = hv;
        hs[(h4*4 + j)*68 + cr*16 + lr] = hv;
      }
  }
  float wv[4];
#pragma unroll
  for (int cr = 0; cr < 4; ++cr) wv[cr] = Whead[cr*16 + lr];
#pragma unroll
  for (int j = 0; j < 4; ++j) {
    float p = 0.f;
#pragma unroll
    for (int cr = 0; cr < 4; ++cr) p = fmaf(hreg[cr][j], wv[cr], p);
    p += __shfl_xor(p, 1, 64);
    p += __shfl_xor(p, 2, 64);
    p += __shfl_xor(p, 4, 64);
    p += __shfl_xor(p, 8, 64);
    if (lr == 0) y[base + h4*4 + j] = p + bhead[0];
  }
}

extern "C" void kernel_launch(void* const* d_in, const int* in_sizes, int n_in,
                              void* d_out, int out_size, void* d_ws, size_t ws_size,
                              hipStream_t stream) {
  const float* x    = (const float*)d_in[0];
  const int*   esrc = (const int*)d_in[1];
  const int*   edst = (const int*)d_in[2];
  const float* eval = (const float*)d_in[3];
  const float* W1   = (const float*)d_in[4];
  const float* b1   = (const float*)d_in[5];
  const float* W2   = (const float*)d_in[6];
  const float* b2   = (const float*)d_in[7];
  const float* Wih  = (const float*)d_in[8];
  const float* Whh  = (const float*)d_in[9];
  const float* bih  = (const float*)d_in[10];
  const float* bhh  = (const float*)d_in[11];
  const float* Whead= (const float*)d_in[12];
  const float* bhead= (const float*)d_in[13];
  int E = in_sizes[1];
  float* y = (float*)d_out;

  char* wsb = (char*)d_ws;
  unsigned short* H1b   = (unsigned short*)(wsb + 0);
  unsigned short* ZB1   = (unsigned short*)(wsb + 20480000);
  unsigned short* OUT2b = (unsigned short*)(wsb + 61440000);
  float* Z1   = (float*)(wsb + 82560000);
  int*   rowp = (int*)(wsb + 83840000);
  int*   cnt  = (int*)(wsb + 83880064);
  int*   csrs = (int*)(wsb + 83920064);
  float* csrv = (float*)(wsb + 84560064);
  unsigned short* Wbih = (unsigned short*)(wsb + 85200064);
  unsigned short* W2t  = (unsigned short*)(wsb + 85224640);
  unsigned short* Whhi = (unsigned short*)(wsb + 85249280);
  unsigned short* Whlo = (unsigned short*)(wsb + 85273856);

  int eb = (E + 255) / 256;

  hipMemsetAsync(cnt, 0, N_NODES*sizeof(int), stream);
  k_count_prep<<<eb + 48, 256, 0, stream>>>(edst, cnt, E, eb, Wih, W2, Whh, Wbih, W2t, Whhi, Whlo);
  k_scan<<<1, 256, 0, stream>>>(cnt, rowp, cnt, N_NODES);
  k_fill<<<eb, 256, 0, stream>>>(esrc, edst, eval, rowp, cnt, csrs, csrv, E);

  k_spmmA<<<625, 256, 0, stream>>>(x, Z1, rowp, csrs, csrv);
  k_spmmB_l1<<<625, 256, 0, stream>>>(x, Z1, rowp, csrs, csrv, W1, b1, H1b);

  k_spmmC<<<5000, 256, 0, stream>>>(H1b, ZB1, rowp, csrs, csrv);
  k_spmmC2_l2m<<<5000, 256, 0, stream>>>(H1b, ZB1, rowp, csrs, csrv, W2t, b2, OUT2b);

  const int gru_lds = 49152 + 4*16*68*4;   // 66560 B -> 2 blocks/CU
  hipFuncSetAttribute((const void*)k_gru, hipFuncAttributeMaxDynamicSharedMemorySize, gru_lds);
  k_gru<<<313, 256, gru_lds, stream>>>(OUT2b, Whhi, Whlo, Wbih, bih, bhh, Whead, bhead, y);
}

// Round 21
// 223.582 us; speedup vs baseline: 1.0410x; 1.0410x over previous
//
#include <hip/hip_runtime.h>
#include <math.h>

#define N_NODES 10000
#define B_SZ 2
#define T_STEPS 8
#define M_COLS 16
#define BN 20000
#define NM 160000

typedef __attribute__((ext_vector_type(8))) short short8;
typedef __attribute__((ext_vector_type(4))) float f32x4;

__device__ __forceinline__ float b2f(unsigned short u) {
  union { unsigned int i; float f; } x; x.i = ((unsigned int)u) << 16; return x.f;
}
__device__ __forceinline__ unsigned short f2b(float f) {
  unsigned int x = __float_as_uint(f);
  return (unsigned short)((x + 0x7fffu + ((x >> 16) & 1u)) >> 16);
}
__device__ __forceinline__ float sigm(float x) {
  return 1.f / (1.f + __expf(-x));
}
__device__ __forceinline__ float tanhfast(float x) {
  float xm = fmaxf(x, -15.f);
  float e = __expf(-2.f * xm);
  return (1.f - e) / (1.f + e);
}

// ---------------- CSR build ----------------
__global__ __launch_bounds__(256) void k_count_prep(const int* __restrict__ dst, int* __restrict__ cnt, int E,
                                                    int eb,
                                                    const float* __restrict__ Wih, const float* __restrict__ W2,
                                                    const float* __restrict__ Whh,
                                                    unsigned short* __restrict__ Wbih,
                                                    unsigned short* __restrict__ W2t,
                                                    unsigned short* __restrict__ Whi,
                                                    unsigned short* __restrict__ Wlo) {
  if ((int)blockIdx.x < eb) {
    int e = blockIdx.x*256 + threadIdx.x;
    if (e < E) atomicAdd(&cnt[dst[e]], 1);
  } else {
    int i = (blockIdx.x - eb)*256 + threadIdx.x;
    if (i >= 12288) return;
    Wbih[i] = f2b(Wih[i]);
    int p = i >> 12, rem = i & 4095, c = rem >> 6, k = rem & 63;
    W2t[i] = f2b(W2[p*4096 + k*64 + c]);
    float v = Whh[i];
    unsigned short h = f2b(v);
    Whi[i] = h;
    Wlo[i] = f2b(v - b2f(h));
  }
}

__global__ __launch_bounds__(256) void k_scan(const int* __restrict__ cntin, int* __restrict__ rowp,
                                              int* __restrict__ cntz, int n) {
  const int K = 40;
  int t = threadIdx.x;
  int beg = t*K;
  int end = beg + K < n ? beg + K : n;
  int s = 0;
  for (int i = beg; i < end; ++i) s += cntin[i];
  int lane = t & 63, w = t >> 6;
  int v = s;
#pragma unroll
  for (int off = 1; off < 64; off <<= 1) {
    int u = __shfl_up(v, off, 64);
    if (lane >= off) v += u;
  }
  __shared__ int wsum[4];
  if (lane == 63) wsum[w] = v;
  __syncthreads();
  int woff = 0;
  for (int i = 0; i < w; ++i) woff += wsum[i];
  int run = woff + v - s;
  for (int i = beg; i < end; ++i) {
    rowp[i] = run;
    run += cntin[i];
    cntz[i] = 0;
  }
  if (t == 255) rowp[n] = run;
}

__global__ __launch_bounds__(256) void k_fill(const int* __restrict__ src, const int* __restrict__ dst,
                                              const float* __restrict__ val, const int* __restrict__ rowp,
                                              int* __restrict__ cur, int* __restrict__ csrs,
                                              float* __restrict__ csrv, int E) {
  int e = blockIdx.x*256 + threadIdx.x;
  if (e >= E) return;
  int d = dst[e];
  int p = atomicAdd(&cur[d], 1);
  int slot = rowp[d] + p;
  csrs[slot] = src[e];
  csrv[slot] = val[e];
}

// ---------------- layer 1 (fused), 4-deep unrolled gathers ----------------
__global__ __launch_bounds__(256) void k_spmmA(const float* __restrict__ x, float* __restrict__ Z1,
                                               const int* __restrict__ rowp, const int* __restrict__ csrs,
                                               const float* __restrict__ csrv) {
  int i = blockIdx.x*256 + threadIdx.x;
  int n = i >> 4, m = i & 15;
  int b = m >> 3, t = m & 7;
  int s = rowp[n], e = rowp[n+1];
  const float* xb = x + b*(N_NODES*T_STEPS) + t;
  float a0 = 0.f, a1 = 0.f, a2 = 0.f, a3 = 0.f;
  int k = s;
  for (; k + 3 < e; k += 4) {
    int s0 = csrs[k], s1 = csrs[k+1], s2 = csrs[k+2], s3 = csrs[k+3];
    float v0 = csrv[k], v1 = csrv[k+1], v2 = csrv[k+2], v3 = csrv[k+3];
    float x0 = xb[s0*T_STEPS], x1 = xb[s1*T_STEPS], x2 = xb[s2*T_STEPS], x3 = xb[s3*T_STEPS];
    a0 = fmaf(v0, x0, a0);
    a1 = fmaf(v1, x1, a1);
    a2 = fmaf(v2, x2, a2);
    a3 = fmaf(v3, x3, a3);
  }
  for (; k < e; ++k) a0 = fmaf(csrv[k], xb[csrs[k]*T_STEPS], a0);
  Z1[i] = (a0 + a1) + (a2 + a3);
}

__global__ __launch_bounds__(256) void k_spmmB_l1(const float* __restrict__ x, const float* __restrict__ Z1,
                                                  const int* __restrict__ rowp, const int* __restrict__ csrs,
                                                  const float* __restrict__ csrv,
                                                  const float* __restrict__ W1, const float* __restrict__ b1,
                                                  unsigned short* __restrict__ H1b) {
  int i = blockIdx.x*256 + threadIdx.x;
  int n = i >> 4, m = i & 15;
  int b = m >> 3, t = m & 7;
  int s = rowp[n], e = rowp[n+1];
  float a0 = 0.f, a1 = 0.f, a2 = 0.f, a3 = 0.f;
  int k = s;
  for (; k + 3 < e; k += 4) {
    int s0 = csrs[k], s1 = csrs[k+1], s2 = csrs[k+2], s3 = csrs[k+3];
    float v0 = csrv[k], v1 = csrv[k+1], v2 = csrv[k+2], v3 = csrv[k+3];
    float g0 = Z1[s0*16 + m], g1 = Z1[s1*16 + m], g2 = Z1[s2*16 + m], g3 = Z1[s3*16 + m];
    a0 = fmaf(v0, g0, a0);
    a1 = fmaf(v1, g1, a1);
    a2 = fmaf(v2, g2, a2);
    a3 = fmaf(v3, g3, a3);
  }
  for (; k < e; ++k) a0 = fmaf(csrv[k], Z1[csrs[k]*16 + m], a0);
  float z2 = (a0 + a1) + (a2 + a3);
  float z0 = x[b*(N_NODES*T_STEPS) + n*T_STEPS + t];
  float z1 = Z1[i];
  unsigned short* dst = H1b + (size_t)i*64;
  union { uint4 v; unsigned short s[8]; } o;
#pragma unroll
  for (int g = 0; g < 8; ++g) {
#pragma unroll
    for (int j = 0; j < 8; ++j) {
      int c = g*8 + j;
      float v = fmaf(z0, W1[c], fmaf(z1, W1[64+c], fmaf(z2, W1[128+c], b1[c])));
      o.s[j] = f2b(v > 0.f ? v : 0.f);
    }
    ((uint4*)dst)[g] = o.v;
  }
}

// ---------------- layer 2 pass 1: chunked spmm, 4-deep unrolled gather ----------------
__global__ __launch_bounds__(256) void k_spmmC(const unsigned short* __restrict__ Zin,
                                               unsigned short* __restrict__ Zout,
                                               const int* __restrict__ rowp, const int* __restrict__ csrs,
                                               const float* __restrict__ csrv) {
  int c = blockIdx.x & 7;
  int grp = blockIdx.x >> 3;
  int n = grp*16 + (threadIdx.x >> 4);
  int l = threadIdx.x & 15;
  int off = c*128 + l*8;
  int s = rowp[n], e = rowp[n+1];
  float acc[8] = {0,0,0,0,0,0,0,0};
  int k = s;
  for (; k + 3 < e; k += 4) {
    int s0 = csrs[k], s1 = csrs[k+1], s2 = csrs[k+2], s3 = csrs[k+3];
    float v0 = csrv[k], v1 = csrv[k+1], v2 = csrv[k+2], v3 = csrv[k+3];
    union { uint4 u; unsigned short s[8]; } z0, z1, z2, z3;
    z0.u = *(const uint4*)(Zin + (size_t)s0*1024 + off);
    z1.u = *(const uint4*)(Zin + (size_t)s1*1024 + off);
    z2.u = *(const uint4*)(Zin + (size_t)s2*1024 + off);
    z3.u = *(const uint4*)(Zin + (size_t)s3*1024 + off);
#pragma unroll
    for (int j = 0; j < 8; ++j)
      acc[j] = fmaf(v3, b2f(z3.s[j]), fmaf(v2, b2f(z2.s[j]),
               fmaf(v1, b2f(z1.s[j]), fmaf(v0, b2f(z0.s[j]), acc[j]))));
  }
  for (; k < e; ++k) {
    int s0 = csrs[k];
    float v0 = csrv[k];
    union { uint4 u; unsigned short s[8]; } z0;
    z0.u = *(const uint4*)(Zin + (size_t)s0*1024 + off);
#pragma unroll
    for (int j = 0; j < 8; ++j) acc[j] = fmaf(v0, b2f(z0.s[j]), acc[j]);
  }
  union { uint4 u; unsigned short s[8]; } o;
#pragma unroll
  for (int j = 0; j < 8; ++j) o.s[j] = f2b(acc[j]);
  *(uint4*)(Zout + (size_t)n*1024 + off) = o.u;
}

// ---------------- layer 2 pass 2 FUSED with dense epilogue ----------------
// 4-deep gather (proven best); phase-2 aH/aZ1 fragment loads HOISTED above the
// barrier (independent of phase 1) so their latency hides under the gather.
__global__ __launch_bounds__(256) void k_spmmC2_l2m(const unsigned short* __restrict__ H1b,
                                                    const unsigned short* __restrict__ ZB1,
                                                    const int* __restrict__ rowp, const int* __restrict__ csrs,
                                                    const float* __restrict__ csrv,
                                                    const unsigned short* __restrict__ Wt,
                                                    const float* __restrict__ b2,
                                                    unsigned short* __restrict__ OUT2b) {
  __shared__ unsigned short Z2L[16][144];
  int c = blockIdx.x & 7;
  int grp = blockIdx.x >> 3;
  int tid = threadIdx.x;
  // phase-2 identities (needed for the hoisted loads)
  int w = tid >> 6, lane = tid & 63;
  int lr = lane & 15, h4 = lane >> 4;
  int q = w & 1, ch = w >> 1;
  int m = 2*c + q;
  // hoisted: issue aH/aZ1 early, consume after barrier
  short8 aH[2], aZ1[2];
#pragma unroll
  for (int kc = 0; kc < 2; ++kc) {
    size_t nm = ((size_t)(grp*16 + lr)*16 + m);
    aH[kc]  = *(const short8*)((const short*)H1b + nm*64 + kc*32 + h4*8);
    aZ1[kc] = *(const short8*)((const short*)ZB1 + nm*64 + kc*32 + h4*8);
  }
  // phase 1: gather chunk c for 16 nodes
  {
    int ni = tid >> 4, l = tid & 15;
    int n = grp*16 + ni;
    int off = c*128 + l*8;
    int s = rowp[n], e = rowp[n+1];
    float acc[8] = {0,0,0,0,0,0,0,0};
    int k = s;
    for (; k + 3 < e; k += 4) {
      int s0 = csrs[k], s1 = csrs[k+1], s2 = csrs[k+2], s3 = csrs[k+3];
      float v0 = csrv[k], v1 = csrv[k+1], v2 = csrv[k+2], v3 = csrv[k+3];
      union { uint4 u; unsigned short s[8]; } z0, z1, z2, z3;
      z0.u = *(const uint4*)(ZB1 + (size_t)s0*1024 + off);
      z1.u = *(const uint4*)(ZB1 + (size_t)s1*1024 + off);
      z2.u = *(const uint4*)(ZB1 + (size_t)s2*1024 + off);
      z3.u = *(const uint4*)(ZB1 + (size_t)s3*1024 + off);
#pragma unroll
      for (int j = 0; j < 8; ++j)
        acc[j] = fmaf(v3, b2f(z3.s[j]), fmaf(v2, b2f(z2.s[j]),
                 fmaf(v1, b2f(z1.s[j]), fmaf(v0, b2f(z0.s[j]), acc[j]))));
    }
    for (; k < e; ++k) {
      int s0 = csrs[k];
      float v0 = csrv[k];
      union { uint4 u; unsigned short s[8]; } z0;
      z0.u = *(const uint4*)(ZB1 + (size_t)s0*1024 + off);
#pragma unroll
      for (int j = 0; j < 8; ++j) acc[j] = fmaf(v0, b2f(z0.s[j]), acc[j]);
    }
    union { uint4 v; unsigned short s[8]; } o;
#pragma unroll
    for (int j = 0; j < 8; ++j) o.s[j] = f2b(acc[j]);
    *(uint4*)&Z2L[ni][(l >> 3)*72 + (l & 7)*8] = o.v;
  }
  __syncthreads();
  // phase 2: wave w -> (q, col-half ch); 16 node-rows x 32 cols
  short8 aZ2[2];
#pragma unroll
  for (int kc = 0; kc < 2; ++kc)
    aZ2[kc] = *(const short8*)&Z2L[lr][q*72 + kc*32 + h4*8];
  const short* Bp = (const short*)Wt;
  f32x4 accb[2];
#pragma unroll
  for (int ct2 = 0; ct2 < 2; ++ct2) {
    int col = (ch*2 + ct2)*16 + lr;
    f32x4 cc = {0.f, 0.f, 0.f, 0.f};
#pragma unroll
    for (int kc = 0; kc < 2; ++kc) {
      short8 b0 = *(const short8*)(Bp + col*64 + kc*32 + h4*8);
      short8 b1 = *(const short8*)(Bp + 4096 + col*64 + kc*32 + h4*8);
      short8 b2f_ = *(const short8*)(Bp + 8192 + col*64 + kc*32 + h4*8);
      cc = __builtin_amdgcn_mfma_f32_16x16x32_bf16(aH[kc],  b0,   cc, 0, 0, 0);
      cc = __builtin_amdgcn_mfma_f32_16x16x32_bf16(aZ1[kc], b1,   cc, 0, 0, 0);
      cc = __builtin_amdgcn_mfma_f32_16x16x32_bf16(aZ2[kc], b2f_, cc, 0, 0, 0);
    }
    accb[ct2] = cc;
  }
  int t = m & 7, bi = m >> 3;
#pragma unroll
  for (int ct2 = 0; ct2 < 2; ++ct2) {
    int col = (ch*2 + ct2)*16 + lr;
    float bb = b2[col];
#pragma unroll
    for (int r = 0; r < 4; ++r) {
      int n2 = grp*16 + h4*4 + r;
      float v = accb[ct2][r] + bb;
      OUT2b[((size_t)((t*2 + bi)*N_NODES + n2))*64 + col] = f2b(v > 0.f ? v : 0.f);
    }
  }
}

// ---------------- fused GRU (FROZEN: r14/r16 exact) ----------------
__global__ __launch_bounds__(256, 2) void k_gru(const unsigned short* __restrict__ OUT2b,
                                                const unsigned short* __restrict__ Whhi,
                                                const unsigned short* __restrict__ Whlo,
                                                const unsigned short* __restrict__ Wihb,
                                                const float* __restrict__ bih,
                                                const float* __restrict__ bhh,
                                                const float* __restrict__ Whead,
                                                const float* __restrict__ bhead,
                                                float* __restrict__ y) {
  extern __shared__ char smem[];
  uint4* WF = (uint4*)smem;
  float* HSb = (float*)(smem + 49152);
  int tid = threadIdx.x;
  for (int idx = tid; idx < 48*64; idx += 256) {
    int f = idx >> 6, ln = idx & 63;
    int lrr = ln & 15, h4r = ln >> 4;
    int g = (f < 24) ? f : f - 24;
    int ct = g >> 1, kc = g & 1;
    const unsigned short* src = (f < 24) ? Whhi : Whlo;
    WF[idx] = *(const uint4*)(src + (ct*16 + lrr)*64 + kc*32 + h4r*8);
  }
  int w = tid >> 6, lane = tid & 63;
  int lr = lane & 15, h4 = lane >> 4;
  float* hs = HSb + w*(16*68);
  for (int i = lane; i < 16*68; i += 64) hs[i] = 0.f;
  __syncthreads();
  int Wv = blockIdx.x*4 + w;
  if (Wv >= 1250) return;
  int base = Wv*16;
  int row0 = base + lr;
  int b0 = row0 >= N_NODES ? 1 : 0;
  int n0 = row0 - b0*N_NODES;

  float cR[4], cZ[4], bNi[4], bNh[4];
#pragma unroll
  for (int cr = 0; cr < 4; ++cr) {
    int col = cr*16 + lr;
    cR[cr]  = bih[col] + bhh[col];
    cZ[cr]  = bih[64+col] + bhh[64+col];
    bNi[cr] = bih[128+col];
    bNh[cr] = bhh[128+col];
  }
  float hreg[4][4];
#pragma unroll
  for (int cr = 0; cr < 4; ++cr)
#pragma unroll
    for (int j = 0; j < 4; ++j) hreg[cr][j] = 0.f;
  const short* O = (const short*)OUT2b;
  const short* Wx = (const short*)Wihb;

#pragma unroll 1
  for (int t = 0; t < 8; ++t) {
    short8 ax[2];
    size_t ab0 = ((size_t)((t*2 + b0)*N_NODES + n0))*64;
    ax[0] = *(const short8*)(O + ab0 + h4*8);
    ax[1] = *(const short8*)(O + ab0 + 32 + h4*8);
    short8 ahi[2], alo[2];
#pragma unroll
    for (int kc = 0; kc < 2; ++kc) {
      const float* hp = hs + lr*68 + kc*32 + h4*8;
      float4 v0 = *(const float4*)hp;
      float4 v1 = *(const float4*)(hp + 4);
      float hv[8];
      hv[0]=v0.x; hv[1]=v0.y; hv[2]=v0.z; hv[3]=v0.w;
      hv[4]=v1.x; hv[5]=v1.y; hv[6]=v1.z; hv[7]=v1.w;
      union { short8 v; unsigned short s[8]; } uh, ul;
#pragma unroll
      for (int j = 0; j < 8; ++j) {
        unsigned short hb = (unsigned short)(__float_as_uint(hv[j]) >> 16);
        uh.s[j] = hb;
        ul.s[j] = f2b(hv[j] - b2f(hb));
      }
      ahi[kc] = uh.v; alo[kc] = ul.v;
    }
    f32x4 aR[4], aZ[4], aNx[4], aNh[4];
#pragma unroll
    for (int cr = 0; cr < 4; ++cr) {
      f32x4 zz = {0.f,0.f,0.f,0.f};
      aR[cr] = zz; aZ[cr] = zz; aNx[cr] = zz; aNh[cr] = zz;
    }
#pragma unroll
    for (int g = 0; g < 6; ++g) {
      short8 fh[4], fl[4], fx[4];
#pragma unroll
      for (int p = 0; p < 4; ++p) {
        int pair = g*4 + p;
        fh[p] = *(const short8*)&WF[pair*64 + lane];
        fl[p] = *(const short8*)&WF[(24 + pair)*64 + lane];
        fx[p] = *(const short8*)(Wx + ((pair >> 1)*16 + lr)*64 + (pair & 1)*32 + h4*8);
      }
      __builtin_amdgcn_sched_barrier(0);
#pragma unroll
      for (int p = 0; p < 4; ++p) {
        int pair = g*4 + p;
        int ct = pair >> 1, kc = pair & 1;
        if (ct < 4) {
          aR[ct] = __builtin_amdgcn_mfma_f32_16x16x32_bf16(ax[kc],  fx[p], aR[ct], 0, 0, 0);
          aR[ct] = __builtin_amdgcn_mfma_f32_16x16x32_bf16(ahi[kc], fh[p], aR[ct], 0, 0, 0);
          aR[ct] = __builtin_amdgcn_mfma_f32_16x16x32_bf16(ahi[kc], fl[p], aR[ct], 0, 0, 0);
          aR[ct] = __builtin_amdgcn_mfma_f32_16x16x32_bf16(alo[kc], fh[p], aR[ct], 0, 0, 0);
        } else if (ct < 8) {
          int cc = ct - 4;
          aZ[cc] = __builtin_amdgcn_mfma_f32_16x16x32_bf16(ax[kc],  fx[p], aZ[cc], 0, 0, 0);
          aZ[cc] = __builtin_amdgcn_mfma_f32_16x16x32_bf16(ahi[kc], fh[p], aZ[cc], 0, 0, 0);
          aZ[cc] = __builtin_amdgcn_mfma_f32_16x16x32_bf16(ahi[kc], fl[p], aZ[cc], 0, 0, 0);
          aZ[cc] = __builtin_amdgcn_mfma_f32_16x16x32_bf16(alo[kc], fh[p], aZ[cc], 0, 0, 0);
        } else {
          int cc = ct - 8;
          aNx[cc] = __builtin_amdgcn_mfma_f32_16x16x32_bf16(ax[kc],  fx[p], aNx[cc], 0, 0, 0);
          aNh[cc] = __builtin_amdgcn_mfma_f32_16x16x32_bf16(ahi[kc], fh[p], aNh[cc], 0, 0, 0);
          aNh[cc] = __builtin_amdgcn_mfma_f32_16x16x32_bf16(ahi[kc], fl[p], aNh[cc], 0, 0, 0);
          aNh[cc] = __builtin_amdgcn_mfma_f32_16x16x32_bf16(alo[kc], fh[p], aNh[cc], 0, 0, 0);
        }
      }
    }
#pragma unroll
    for (int cr = 0; cr < 4; ++cr)
#pragma unroll
      for (int j = 0; j < 4; ++j) {
        float r = sigm(aR[cr][j] + cR[cr]);
        float z = sigm(aZ[cr][j] + cZ[cr]);
        float nn = tanhfast(aNx[cr][j] + bNi[cr] + r*(aNh[cr][j] + bNh[cr]));
        float hv = (1.f - z)*nn + z*hreg[cr][j];
        hreg[cr][j] = hv;
        hs[(h4*4 + j)*68 + cr*16 + lr] = hv;
      }
  }
  float wv[4];
#pragma unroll
  for (int cr = 0; cr < 4; ++cr) wv[cr] = Whead[cr*16 + lr];
#pragma unroll
  for (int j = 0; j < 4; ++j) {
    float p = 0.f;
#pragma unroll
    for (int cr = 0; cr < 4; ++cr) p = fmaf(hreg[cr][j], wv[cr], p);
    p += __shfl_xor(p, 1, 64);
    p += __shfl_xor(p, 2, 64);
    p += __shfl_xor(p, 4, 64);
    p += __shfl_xor(p, 8, 64);
    if (lr == 0) y[base + h4*4 + j] = p + bhead[0];
  }
}

extern "C" void kernel_launch(void* const* d_in, const int* in_sizes, int n_in,
                              void* d_out, int out_size, void* d_ws, size_t ws_size,
                              hipStream_t stream) {
  const float* x    = (const float*)d_in[0];
  const int*   esrc = (const int*)d_in[1];
  const int*   edst = (const int*)d_in[2];
  const float* eval = (const float*)d_in[3];
  const float* W1   = (const float*)d_in[4];
  const float* b1   = (const float*)d_in[5];
  const float* W2   = (const float*)d_in[6];
  const float* b2   = (const float*)d_in[7];
  const float* Wih  = (const float*)d_in[8];
  const float* Whh  = (const float*)d_in[9];
  const float* bih  = (const float*)d_in[10];
  const float* bhh  = (const float*)d_in[11];
  const float* Whead= (const float*)d_in[12];
  const float* bhead= (const float*)d_in[13];
  int E = in_sizes[1];
  float* y = (float*)d_out;

  char* wsb = (char*)d_ws;
  unsigned short* H1b   = (unsigned short*)(wsb + 0);
  unsigned short* ZB1   = (unsigned short*)(wsb + 20480000);
  unsigned short* OUT2b = (unsigned short*)(wsb + 61440000);
  float* Z1   = (float*)(wsb + 82560000);
  int*   rowp = (int*)(wsb + 83840000);
  int*   cnt  = (int*)(wsb + 83880064);
  int*   csrs = (int*)(wsb + 83920064);
  float* csrv = (float*)(wsb + 84560064);
  unsigned short* Wbih = (unsigned short*)(wsb + 85200064);
  unsigned short* W2t  = (unsigned short*)(wsb + 85224640);
  unsigned short* Whhi = (unsigned short*)(wsb + 85249280);
  unsigned short* Whlo = (unsigned short*)(wsb + 85273856);

  int eb = (E + 255) / 256;

  hipMemsetAsync(cnt, 0, N_NODES*sizeof(int), stream);
  k_count_prep<<<eb + 48, 256, 0, stream>>>(edst, cnt, E, eb, Wih, W2, Whh, Wbih, W2t, Whhi, Whlo);
  k_scan<<<1, 256, 0, stream>>>(cnt, rowp, cnt, N_NODES);
  k_fill<<<eb, 256, 0, stream>>>(esrc, edst, eval, rowp, cnt, csrs, csrv, E);

  k_spmmA<<<625, 256, 0, stream>>>(x, Z1, rowp, csrs, csrv);
  k_spmmB_l1<<<625, 256, 0, stream>>>(x, Z1, rowp, csrs, csrv, W1, b1, H1b);

  k_spmmC<<<5000, 256, 0, stream>>>(H1b, ZB1, rowp, csrs, csrv);
  k_spmmC2_l2m<<<5000, 256, 0, stream>>>(H1b, ZB1, rowp, csrs, csrv, W2t, b2, OUT2b);

  const int gru_lds = 49152 + 4*16*68*4;   // 66560 B -> 2 blocks/CU
  hipFuncSetAttribute((const void*)k_gru, hipFuncAttributeMaxDynamicSharedMemorySize, gru_lds);
  k_gru<<<313, 256, gru_lds, stream>>>(OUT2b, Whhi, Whlo, Wbih, bih, bhh, Whead, bhead, y);
}